// Round 4
// baseline (24.275 us; speedup 1.0000x reference)
//
#include <hip/hip_runtime.h>
#include <cstdint>

#define NPTS 512
#define DIM 256
#define NBLK (NPTS / 2)
#define MARGIN_F 0.2f
#define FIX_SCALE 1073741824.0   // 2^30
#define SUM_BITS 42
#define CNT_SHIFT 42
#define DONE_SHIFT 56

__device__ __forceinline__ uint32_t rotl32(uint32_t x, uint32_t r) {
  return (x << r) | (x >> (32u - r));
}

// JAX threefry2x32, key (0, 42), partitionable mode: bits = out0 ^ out1,
// counter x = (hi32(m)=0, lo32(m)=m). Verified bit-exact (absmax 0.0, r1-r3).
__device__ __forceinline__ uint32_t threefry_bits(uint32_t c1) {
  const uint32_t k0 = 0u, k1 = 42u;
  const uint32_t k2 = k0 ^ k1 ^ 0x1BD11BDAu;
  uint32_t x0 = 0u + k0;
  uint32_t x1 = c1 + k1;
#define TFR(r) { x0 += x1; x1 = rotl32(x1, r); x1 ^= x0; }
  TFR(13u) TFR(15u) TFR(26u) TFR(6u)
  x0 += k1; x1 += k2 + 1u;
  TFR(17u) TFR(29u) TFR(16u) TFR(24u)
  x0 += k2; x1 += k0 + 2u;
  TFR(13u) TFR(15u) TFR(26u) TFR(6u)
  x0 += k0; x1 += k1 + 3u;
  TFR(17u) TFR(29u) TFR(16u) TFR(24u)
  x0 += k1; x1 += k2 + 4u;
  TFR(13u) TFR(15u) TFR(26u) TFR(6u)
  x0 += k2; x1 += k0 + 5u;
#undef TFR
  return x0 ^ x1;
}

// One block per 2 anchors, 512 threads = 8 waves. One packed u64 atomicAdd
// per block; the block that completes the count (done field == NBLK-1)
// finalizes the loss inline. acc must be zeroed before launch (8B memset).
__global__ __launch_bounds__(512) void triplet_main(
    const float* __restrict__ emb,
    const int* __restrict__ labels,
    unsigned long long* __restrict__ acc,
    float* __restrict__ out)
{
  __shared__ float sea0[DIM];
  __shared__ float sea1[DIM];
  __shared__ float sd0[NPTS];   // dot(a0, j) -> then sqd(a0, j)
  __shared__ float sd1[NPTS];   // dot(a1, j) -> then sqd(a1, j)
  __shared__ float snrm[NPTS];  // ||j||^2
  __shared__ int   slab[NPTS];
  __shared__ int   plist[128];  // packed (ai<<16)|p positive pairs
  __shared__ int   pcnt;
  __shared__ unsigned long long wsum[8], wcnt[8];

  const int a0 = blockIdx.x * 2;
  const int a1 = a0 + 1;
  const int t = threadIdx.x;
  const int wave = t >> 6;
  const int lane = t & 63;
  const int grp = lane >> 4;    // 0..3  (16-lane group -> one j row)
  const int l16 = lane & 15;

  // ---- Phase 1: stage anchors + labels ----
  if (t < 256)       sea0[t]       = emb[a0 * DIM + t];
  else               sea1[t - 256] = emb[a1 * DIM + (t - 256)];
  slab[t] = labels[t];
  if (t == 0) pcnt = 0;
  __syncthreads();

  // Anchor slices -> registers (invariant over all rounds).
  float4 A0[4], A1[4];
  #pragma unroll
  for (int it = 0; it < 4; ++it) {
    const int d = (it << 6) + (l16 << 2);
    A0[it] = *reinterpret_cast<const float4*>(sea0 + d);
    A1[it] = *reinterpret_cast<const float4*>(sea1 + d);
  }

  // ---- Phase 2: cooperative distances. Wave w owns j in [w*64, w*64+64).
  // 16-lane group per j; lanes split the 256-dim axis in float4 chunks.
  #pragma unroll 4
  for (int round = 0; round < 16; ++round) {
    const int j = (wave << 6) + (round << 2) + grp;
    const float4* rj = reinterpret_cast<const float4*>(emb + j * DIM);
    float4 v[4];
    #pragma unroll
    for (int it = 0; it < 4; ++it) v[it] = rj[(it << 4) + l16];

    float s0 = 0.f, s1 = 0.f, q = 0.f;
    #pragma unroll
    for (int it = 0; it < 4; ++it) {
      s0 += v[it].x * A0[it].x + v[it].y * A0[it].y + v[it].z * A0[it].z + v[it].w * A0[it].w;
      s1 += v[it].x * A1[it].x + v[it].y * A1[it].y + v[it].z * A1[it].z + v[it].w * A1[it].w;
      q  += v[it].x * v[it].x  + v[it].y * v[it].y  + v[it].z * v[it].z  + v[it].w * v[it].w;
    }
    #pragma unroll
    for (int m = 8; m; m >>= 1) {
      s0 += __shfl_xor(s0, m);
      s1 += __shfl_xor(s1, m);
      q  += __shfl_xor(q, m);
    }
    if (l16 == 0) { sd0[j] = s0; sd1[j] = s1; snrm[j] = q; }
  }
  __syncthreads();

  // ---- Phase 2.5: dots -> squared distances; build positive-pair list ----
  {
    const float na0 = snrm[a0];
    const float na1 = snrm[a1];
    const float nj = snrm[t];
    const float v0 = na0 + nj - 2.f * sd0[t];
    const float v1 = na1 + nj - 2.f * sd1[t];
    __syncthreads();  // all reads of sd done before overwrite
    sd0[t] = v0 > 0.f ? v0 : 0.f;
    sd1[t] = v1 > 0.f ? v1 : 0.f;
    const int lp = slab[t];
    if (t != a0 && lp == slab[a0]) { int k = atomicAdd(&pcnt, 1); plist[k] = t; }
    if (t != a1 && lp == slab[a1]) { int k = atomicAdd(&pcnt, 1); plist[k] = (1 << 16) | t; }
  }
  __syncthreads();

  // ---- Phase 3: semi-hard scan + threefry argmax per positive pair ----
  unsigned long long lsum = 0ull, lcnt = 0ull;
  const int np = pcnt;
  for (int e = wave; e < np; e += 8) {
    const int ent = plist[e];
    const int ai = ent >> 16;
    const int p = ent & 0xffff;
    const float* drp = ai ? sd1 : sd0;
    const int ag = ai ? a1 : a0;
    const int la = slab[ag];
    const float dap = drp[p];
    const float hi = dap + MARGIN_F;
    const uint32_t base = ((uint32_t)ag << 18) | ((uint32_t)p << 9);

    int bestKey = -1, bestJ = 0;
    #pragma unroll
    for (int k = 0; k < 8; ++k) {
      const int j = lane + (k << 6);
      const float dj = drp[j];
      if (slab[j] != la && dj > dap && dj < hi) {
        const int key = (int)(threefry_bits(base + (uint32_t)j) >> 9);
        if (key > bestKey) { bestKey = key; bestJ = j; }
      }
    }
    #pragma unroll
    for (int m = 32; m; m >>= 1) {
      const int ok = __shfl_xor(bestKey, m);
      const int oj = __shfl_xor(bestJ, m);
      if (ok > bestKey || (ok == bestKey && oj < bestJ)) { bestKey = ok; bestJ = oj; }
    }
    if (lane == 0 && bestKey >= 0) {
      const float term = (dap - drp[bestJ]) + MARGIN_F;
      lsum += (unsigned long long)((double)term * FIX_SCALE + 0.5);
      lcnt += 1ull;
    }
  }

  // ---- Block reduce (integer, fixed order), then one packed atomic ----
  if (lane == 0) { wsum[wave] = lsum; wcnt[wave] = lcnt; }
  __syncthreads();
  if (t == 0) {
    unsigned long long s = 0ull, c = 0ull;
    #pragma unroll
    for (int w = 0; w < 8; ++w) { s += wsum[w]; c += wcnt[w]; }
    const unsigned long long contrib =
        (1ull << DONE_SHIFT) | (c << CNT_SHIFT) | s;
    const unsigned long long old = atomicAdd(acc, contrib);
    if ((old >> DONE_SHIFT) == (unsigned long long)(NBLK - 1)) {
      // last block to finish: finalize inline
      const unsigned long long tot = old + contrib;
      const unsigned long long sum = tot & ((1ull << SUM_BITS) - 1ull);
      const unsigned long long cnt = (tot >> CNT_SHIFT) & 0x3FFFull;
      const double sd = (double)sum / FIX_SCALE;
      const double cd = cnt ? (double)cnt : 1.0;
      out[0] = (float)(sd / cd);
    }
  }
}

extern "C" void kernel_launch(void* const* d_in, const int* in_sizes, int n_in,
                              void* d_out, int out_size, void* d_ws, size_t ws_size,
                              hipStream_t stream) {
  const float* emb  = (const float*)d_in[0];
  const int* labels = (const int*)d_in[1];
  float* out        = (float*)d_out;
  unsigned long long* acc = (unsigned long long*)d_ws;

  hipMemsetAsync(d_ws, 0, sizeof(unsigned long long), stream);
  triplet_main<<<dim3(NBLK), dim3(512), 0, stream>>>(emb, labels, acc, out);
}

// Round 5
// 22.091 us; speedup vs baseline: 1.0989x; 1.0989x over previous
//
#include <hip/hip_runtime.h>
#include <cstdint>

#define NPTS 512
#define DIM 256
#define NBLK (NPTS / 2)
#define WAVES 16
#define MARGIN_F 0.2f
#define FIX_SCALE 1073741824.0   // 2^30
#define SUM_BITS 42
#define CNT_SHIFT 42
#define DONE_SHIFT 56

__device__ __forceinline__ uint32_t rotl32(uint32_t x, uint32_t r) {
  return (x << r) | (x >> (32u - r));
}

// JAX threefry2x32, key (0, 42), partitionable mode: bits = out0 ^ out1,
// counter x = (hi32(m)=0, lo32(m)=m). Verified bit-exact (absmax 0.0, r1-r4).
__device__ __forceinline__ uint32_t threefry_bits(uint32_t c1) {
  const uint32_t k0 = 0u, k1 = 42u;
  const uint32_t k2 = k0 ^ k1 ^ 0x1BD11BDAu;
  uint32_t x0 = 0u + k0;
  uint32_t x1 = c1 + k1;
#define TFR(r) { x0 += x1; x1 = rotl32(x1, r); x1 ^= x0; }
  TFR(13u) TFR(15u) TFR(26u) TFR(6u)
  x0 += k1; x1 += k2 + 1u;
  TFR(17u) TFR(29u) TFR(16u) TFR(24u)
  x0 += k2; x1 += k0 + 2u;
  TFR(13u) TFR(15u) TFR(26u) TFR(6u)
  x0 += k0; x1 += k1 + 3u;
  TFR(17u) TFR(29u) TFR(16u) TFR(24u)
  x0 += k1; x1 += k2 + 4u;
  TFR(13u) TFR(15u) TFR(26u) TFR(6u)
  x0 += k2; x1 += k0 + 5u;
#undef TFR
  return x0 ^ x1;
}

// One block per 2 anchors, 1024 threads = 16 waves (4 waves/SIMD for latency
// hiding). One packed u64 atomicAdd per block; the block that completes the
// done-count finalizes the loss inline. acc must be zeroed before launch.
__global__ __launch_bounds__(1024) void triplet_main(
    const float* __restrict__ emb,
    const int* __restrict__ labels,
    unsigned long long* __restrict__ acc,
    float* __restrict__ out)
{
  __shared__ float sea0[DIM];
  __shared__ float sea1[DIM];
  __shared__ float sd0[NPTS];   // dot(a0, j) -> then sqd(a0, j)
  __shared__ float sd1[NPTS];   // dot(a1, j) -> then sqd(a1, j)
  __shared__ float snrm[NPTS];  // ||j||^2
  __shared__ int   slab[NPTS];
  __shared__ int   plist[128];  // packed (ai<<16)|p positive pairs
  __shared__ int   pcnt;
  __shared__ unsigned long long wsum[WAVES], wcnt[WAVES];

  const int a0 = blockIdx.x * 2;
  const int a1 = a0 + 1;
  const int t = threadIdx.x;
  const int wave = t >> 6;
  const int lane = t & 63;
  const int grp = lane >> 4;    // 0..3  (16-lane group -> one j row)
  const int l16 = lane & 15;

  // ---- Phase 1: stage anchors + labels ----
  if (t < 256)      sea0[t] = emb[a0 * DIM + t];
  else if (t < 512) sea1[t - 256] = emb[a1 * DIM + (t - 256)];
  if (t < 512)      slab[t] = labels[t];
  if (t == 0) pcnt = 0;
  __syncthreads();

  // Anchor slices -> registers (invariant across rounds; halves LDS traffic).
  float4 A0[4], A1[4];
  #pragma unroll
  for (int it = 0; it < 4; ++it) {
    const int d = (it << 6) + (l16 << 2);
    A0[it] = *reinterpret_cast<const float4*>(sea0 + d);
    A1[it] = *reinterpret_cast<const float4*>(sea1 + d);
  }

  // ---- Phase 2: cooperative distances. Wave w owns j in [w*32, w*32+32).
  // 16-lane group per j; lanes split the 256-dim axis in float4 chunks.
  #pragma unroll 2
  for (int round = 0; round < 8; ++round) {
    const int j = (wave << 5) + (round << 2) + grp;
    float s0 = 0.f, s1 = 0.f, q = 0.f;
    #pragma unroll
    for (int it = 0; it < 4; ++it) {
      const int d = (it << 6) + (l16 << 2);
      const float4 v = *reinterpret_cast<const float4*>(emb + j * DIM + d);
      s0 += v.x * A0[it].x + v.y * A0[it].y + v.z * A0[it].z + v.w * A0[it].w;
      s1 += v.x * A1[it].x + v.y * A1[it].y + v.z * A1[it].z + v.w * A1[it].w;
      q  += v.x * v.x  + v.y * v.y  + v.z * v.z  + v.w * v.w;
    }
    #pragma unroll
    for (int m = 8; m; m >>= 1) {
      s0 += __shfl_xor(s0, m);
      s1 += __shfl_xor(s1, m);
      q  += __shfl_xor(q, m);
    }
    if (l16 == 0) { sd0[j] = s0; sd1[j] = s1; snrm[j] = q; }
  }
  __syncthreads();

  // ---- Phase 2.5: dots -> squared distances; build positive-pair list ----
  float v0 = 0.f, v1 = 0.f;
  if (t < 512) {
    const float na0 = snrm[a0];
    const float na1 = snrm[a1];
    const float nj = snrm[t];
    v0 = na0 + nj - 2.f * sd0[t];
    v1 = na1 + nj - 2.f * sd1[t];
  }
  __syncthreads();  // all reads of sd done before overwrite
  if (t < 512) {
    sd0[t] = v0 > 0.f ? v0 : 0.f;
    sd1[t] = v1 > 0.f ? v1 : 0.f;
    const int lp = slab[t];
    if (t != a0 && lp == slab[a0]) { int k = atomicAdd(&pcnt, 1); plist[k] = t; }
    if (t != a1 && lp == slab[a1]) { int k = atomicAdd(&pcnt, 1); plist[k] = (1 << 16) | t; }
  }
  __syncthreads();

  // ---- Phase 3: semi-hard scan + threefry argmax per positive pair ----
  unsigned long long lsum = 0ull, lcnt = 0ull;
  const int np = pcnt;
  for (int e = wave; e < np; e += WAVES) {
    const int ent = plist[e];
    const int ai = ent >> 16;
    const int p = ent & 0xffff;
    const float* drp = ai ? sd1 : sd0;
    const int ag = ai ? a1 : a0;
    const int la = slab[ag];
    const float dap = drp[p];
    const float hi = dap + MARGIN_F;
    const uint32_t base = ((uint32_t)ag << 18) | ((uint32_t)p << 9);

    int bestKey = -1, bestJ = 0;
    #pragma unroll
    for (int k = 0; k < 8; ++k) {
      const int j = lane + (k << 6);
      const float dj = drp[j];
      if (slab[j] != la && dj > dap && dj < hi) {
        const int key = (int)(threefry_bits(base + (uint32_t)j) >> 9);
        if (key > bestKey) { bestKey = key; bestJ = j; }
      }
    }
    #pragma unroll
    for (int m = 32; m; m >>= 1) {
      const int ok = __shfl_xor(bestKey, m);
      const int oj = __shfl_xor(bestJ, m);
      if (ok > bestKey || (ok == bestKey && oj < bestJ)) { bestKey = ok; bestJ = oj; }
    }
    if (lane == 0 && bestKey >= 0) {
      const float term = (dap - drp[bestJ]) + MARGIN_F;
      lsum += (unsigned long long)((double)term * FIX_SCALE + 0.5);
      lcnt += 1ull;
    }
  }

  // ---- Block reduce (integer, fixed order), then one packed atomic ----
  if (lane == 0) { wsum[wave] = lsum; wcnt[wave] = lcnt; }
  __syncthreads();
  if (t == 0) {
    unsigned long long s = 0ull, c = 0ull;
    #pragma unroll
    for (int w = 0; w < WAVES; ++w) { s += wsum[w]; c += wcnt[w]; }
    const unsigned long long contrib =
        (1ull << DONE_SHIFT) | (c << CNT_SHIFT) | s;
    const unsigned long long old = atomicAdd(acc, contrib);
    if ((old >> DONE_SHIFT) == (unsigned long long)(NBLK - 1)) {
      const unsigned long long tot = old + contrib;
      const unsigned long long sum = tot & ((1ull << SUM_BITS) - 1ull);
      const unsigned long long cnt = (tot >> CNT_SHIFT) & 0x3FFFull;
      const double sd = (double)sum / FIX_SCALE;
      const double cd = cnt ? (double)cnt : 1.0;
      out[0] = (float)(sd / cd);
    }
  }
}

extern "C" void kernel_launch(void* const* d_in, const int* in_sizes, int n_in,
                              void* d_out, int out_size, void* d_ws, size_t ws_size,
                              hipStream_t stream) {
  const float* emb  = (const float*)d_in[0];
  const int* labels = (const int*)d_in[1];
  float* out        = (float*)d_out;
  unsigned long long* acc = (unsigned long long*)d_ws;

  hipMemsetAsync(d_ws, 0, sizeof(unsigned long long), stream);
  triplet_main<<<dim3(NBLK), dim3(1024), 0, stream>>>(emb, labels, acc, out);
}

// Round 6
// 18.754 us; speedup vs baseline: 1.2944x; 1.1779x over previous
//
#include <hip/hip_runtime.h>
#include <cstdint>

#define NPTS 512
#define DIM 256
#define NBLK (NPTS / 2)
#define TK 32
#define LDSW 132            // padded LDS row stride (floats): 16B-aligned, conflict-free
#define MARGIN_F 0.2f
#define FIX_SCALE 1073741824.0   // 2^30
#define SUM_BITS 42
#define CNT_SHIFT 42
#define DONE_SHIFT 56

__device__ __forceinline__ uint32_t rotl32(uint32_t x, uint32_t r) {
  return (x << r) | (x >> (32u - r));
}

// JAX threefry2x32, key (0, 42), partitionable mode: bits = out0 ^ out1,
// counter x = (hi32(m)=0, lo32(m)=m). Verified bit-exact (absmax 0.0, r1-r5).
__device__ __forceinline__ uint32_t threefry_bits(uint32_t c1) {
  const uint32_t k0 = 0u, k1 = 42u;
  const uint32_t k2 = k0 ^ k1 ^ 0x1BD11BDAu;
  uint32_t x0 = 0u + k0;
  uint32_t x1 = c1 + k1;
#define TFR(r) { x0 += x1; x1 = rotl32(x1, r); x1 ^= x0; }
  TFR(13u) TFR(15u) TFR(26u) TFR(6u)
  x0 += k1; x1 += k2 + 1u;
  TFR(17u) TFR(29u) TFR(16u) TFR(24u)
  x0 += k2; x1 += k0 + 2u;
  TFR(13u) TFR(15u) TFR(26u) TFR(6u)
  x0 += k0; x1 += k1 + 3u;
  TFR(17u) TFR(29u) TFR(16u) TFR(24u)
  x0 += k1; x1 += k2 + 4u;
  TFR(13u) TFR(15u) TFR(26u) TFR(6u)
  x0 += k2; x1 += k0 + 5u;
#undef TFR
  return x0 ^ x1;
}

// ---- K1: Gram matrix. 16x16 grid of 32x32 tiles, 512 threads/block. ----
// Thread (ty,tx) ty=0..31, tx=0..15 computes G[ti*32+ty][tj*32 + {tx, tx+16}].
// LDS tiles staged in two k-halves (128 dims each), padded stride 132:
//  - As read: 4 distinct ty/wave -> banks {0,4,8,12}+span4, 16-lane broadcast.
//  - Bs read: 16 tx -> 8 bank-groups, 2-way (free per m136); row tx+16 same.
__global__ __launch_bounds__(512) void gram_kernel(
    const float* __restrict__ emb,
    float* __restrict__ G,
    float* __restrict__ dg,
    unsigned long long* __restrict__ gsum)
{
  __shared__ float As[TK][LDSW];
  __shared__ float Bs[TK][LDSW];

  const int b = blockIdx.x;
  const int ti = b >> 4, tj = b & 15;
  const int t = threadIdx.x;
  const int ty = t >> 4;     // 0..31
  const int tx = t & 15;     // 0..15

  if (b == 0 && t == 0) *gsum = 0ull;   // replaces the memset dispatch

  float acc0 = 0.f, acc1 = 0.f;
  #pragma unroll
  for (int kh = 0; kh < 2; ++kh) {
    const int koff = kh << 7;   // 0, 128
    __syncthreads();            // protect As/Bs against overwrite
    // stage A,B tiles: 1024 float4 each / 512 threads = 2 per thread
    #pragma unroll
    for (int q = 0; q < 2; ++q) {
      const int f = t * 2 + q;
      const int r = f >> 5;       // tile row
      const int c4 = f & 31;      // float4 within k-half
      const float4 va = *reinterpret_cast<const float4*>(emb + (ti * TK + r) * DIM + koff + c4 * 4);
      const float4 vb = *reinterpret_cast<const float4*>(emb + (tj * TK + r) * DIM + koff + c4 * 4);
      *reinterpret_cast<float4*>(&As[r][c4 * 4]) = va;
      *reinterpret_cast<float4*>(&Bs[r][c4 * 4]) = vb;
    }
    __syncthreads();
    #pragma unroll 8
    for (int k4 = 0; k4 < 32; ++k4) {
      const float4 a  = *reinterpret_cast<const float4*>(&As[ty][k4 * 4]);
      const float4 b0 = *reinterpret_cast<const float4*>(&Bs[tx][k4 * 4]);
      const float4 b1 = *reinterpret_cast<const float4*>(&Bs[tx + 16][k4 * 4]);
      acc0 += a.x * b0.x + a.y * b0.y + a.z * b0.z + a.w * b0.w;
      acc1 += a.x * b1.x + a.y * b1.y + a.z * b1.z + a.w * b1.w;
    }
  }
  const int gr = ti * TK + ty;
  const int gc0 = tj * TK + tx;
  G[gr * NPTS + gc0]      = acc0;
  G[gr * NPTS + gc0 + 16] = acc1;
  if (ti == tj) {
    if (ty == tx)           dg[gr] = acc0;   // rows 0..15 of tile
    else if (ty == tx + 16) dg[gr] = acc1;   // rows 16..31
  }
}

// ---- K2: semi-hard scan. One block per 2 anchors, 512 threads = 8 waves. --
__global__ __launch_bounds__(512) void semihard_kernel(
    const float* __restrict__ G,
    const float* __restrict__ dg,
    const int* __restrict__ labels,
    unsigned long long* __restrict__ gsum,
    float* __restrict__ out)
{
  __shared__ float sd0[NPTS];
  __shared__ float sd1[NPTS];
  __shared__ int   slab[NPTS];
  __shared__ int   plist[256];
  __shared__ int   pcnt;
  __shared__ unsigned long long wsum[8], wcnt[8];

  const int a0 = blockIdx.x * 2;
  const int a1 = a0 + 1;
  const int t = threadIdx.x;
  const int wave = t >> 6;
  const int lane = t & 63;

  if (t == 0) pcnt = 0;

  // Reconstruct the two sqd rows from Gram + diagonal (6 KB of reads).
  {
    const float da0 = dg[a0];
    const float da1 = dg[a1];
    const float dt  = dg[t];
    const float g0 = G[a0 * NPTS + t];
    const float g1 = G[a1 * NPTS + t];
    slab[t] = labels[t];
    const float v0 = da0 + dt - 2.f * g0;
    const float v1 = da1 + dt - 2.f * g1;
    sd0[t] = v0 > 0.f ? v0 : 0.f;
    sd1[t] = v1 > 0.f ? v1 : 0.f;
  }
  __syncthreads();

  // positive-pair list
  {
    const int lp = slab[t];
    if (t != a0 && lp == slab[a0]) { int k = atomicAdd(&pcnt, 1); plist[k] = t; }
    if (t != a1 && lp == slab[a1]) { int k = atomicAdd(&pcnt, 1); plist[k] = (1 << 16) | t; }
  }
  __syncthreads();

  // semi-hard scan + threefry argmax per positive pair
  unsigned long long lsum = 0ull, lcnt = 0ull;
  const int np = pcnt;
  for (int e = wave; e < np; e += 8) {
    const int ent = plist[e];
    const int ai = ent >> 16;
    const int p = ent & 0xffff;
    const float* drp = ai ? sd1 : sd0;
    const int ag = ai ? a1 : a0;
    const int la = slab[ag];
    const float dap = drp[p];
    const float hi = dap + MARGIN_F;
    const uint32_t base = ((uint32_t)ag << 18) | ((uint32_t)p << 9);

    int bestKey = -1, bestJ = 0;
    #pragma unroll
    for (int k = 0; k < 8; ++k) {
      const int j = lane + (k << 6);
      const float dj = drp[j];
      if (slab[j] != la && dj > dap && dj < hi) {
        const int key = (int)(threefry_bits(base + (uint32_t)j) >> 9);
        if (key > bestKey) { bestKey = key; bestJ = j; }
      }
    }
    #pragma unroll
    for (int m = 32; m; m >>= 1) {
      const int ok = __shfl_xor(bestKey, m);
      const int oj = __shfl_xor(bestJ, m);
      if (ok > bestKey || (ok == bestKey && oj < bestJ)) { bestKey = ok; bestJ = oj; }
    }
    if (lane == 0 && bestKey >= 0) {
      const float term = (dap - drp[bestJ]) + MARGIN_F;
      lsum += (unsigned long long)((double)term * FIX_SCALE + 0.5);
      lcnt += 1ull;
    }
  }

  // block reduce (integer, fixed order) -> one packed atomic
  if (lane == 0) { wsum[wave] = lsum; wcnt[wave] = lcnt; }
  __syncthreads();
  if (t == 0) {
    unsigned long long s = 0ull, c = 0ull;
    #pragma unroll
    for (int w = 0; w < 8; ++w) { s += wsum[w]; c += wcnt[w]; }
    const unsigned long long contrib =
        (1ull << DONE_SHIFT) | (c << CNT_SHIFT) | s;
    const unsigned long long old = atomicAdd(gsum, contrib);
    if ((old >> DONE_SHIFT) == (unsigned long long)(NBLK - 1)) {
      const unsigned long long tot = old + contrib;
      const unsigned long long sum = tot & ((1ull << SUM_BITS) - 1ull);
      const unsigned long long cnt = (tot >> CNT_SHIFT) & 0x3FFFull;
      const double sd = (double)sum / FIX_SCALE;
      const double cd = cnt ? (double)cnt : 1.0;
      out[0] = (float)(sd / cd);
    }
  }
}

extern "C" void kernel_launch(void* const* d_in, const int* in_sizes, int n_in,
                              void* d_out, int out_size, void* d_ws, size_t ws_size,
                              hipStream_t stream) {
  const float* emb  = (const float*)d_in[0];
  const int* labels = (const int*)d_in[1];
  float* out        = (float*)d_out;

  float* G  = (float*)d_ws;                                  // 512*512 f32 = 1 MB
  float* dg = (float*)((char*)d_ws + NPTS * NPTS * 4);       // 512 f32
  unsigned long long* gsum =
      (unsigned long long*)((char*)d_ws + NPTS * NPTS * 4 + 2048);

  gram_kernel<<<dim3(256), dim3(512), 0, stream>>>(emb, G, dg, gsum);
  semihard_kernel<<<dim3(NBLK), dim3(512), 0, stream>>>(G, dg, labels, gsum, out);
}